// Round 12
// baseline (185.477 us; speedup 1.0000x reference)
//
#include <hip/hip_runtime.h>
#include <hip/hip_bf16.h>

#define D 128
#define CAT 640
#define BM 32
#define W1F_ELEMS 81920    // 20*8*64*8
#define W2F_ELEMS 16384    // 4*8*64*8

typedef __attribute__((ext_vector_type(8))) short bf16x8;
typedef __attribute__((ext_vector_type(4))) float f32x4;

static __device__ __forceinline__ unsigned short f32_to_bf16(float f) {
    unsigned u = __float_as_uint(f);
    unsigned r = u + 0x7FFFu + ((u >> 16) & 1u);   // RNE
    return (unsigned short)(r >> 16);
}

static __device__ __forceinline__ unsigned pack_bf16x2(float a, float b) {
    __hip_bfloat162 h = __float22bfloat162_rn(make_float2(a, b));  // v_cvt_pk_bf16_f32
    return *reinterpret_cast<unsigned*>(&h);
}

// async global->LDS, 16B per lane, wave-uniform LDS base + lane*16
static __device__ __forceinline__ void gload_lds16(const float* g, void* lds) {
    __builtin_amdgcn_global_load_lds(
        (const __attribute__((address_space(1))) void*)g,
        (__attribute__((address_space(3))) void*)lds, 16, 0, 0);
}

// Pack W1 [128][640] and W2 [128][128] (fp32, torch Linear [out,in]) into MFMA
// B-fragment order: (ks, j16, lane, e) = W[j16*16 + (lane&15)][ks*32 + (lane>>4)*8 + e]
__global__ void prep_frags(const float* __restrict__ W1, const float* __restrict__ W2,
                           unsigned short* __restrict__ W1f, unsigned short* __restrict__ W2f) {
    int f = blockIdx.x * 256 + threadIdx.x;
    if (f < W1F_ELEMS) {
        int e = f & 7, l = (f >> 3) & 63, j16 = (f >> 9) & 7, ks = f >> 12;
        int o = j16 * 16 + (l & 15);
        int k = ks * 32 + ((l >> 4) << 3) + e;
        W1f[f] = f32_to_bf16(W1[o * CAT + k]);
    } else if (f < W1F_ELEMS + W2F_ELEMS) {
        int f2 = f - W1F_ELEMS;
        int e = f2 & 7, l = (f2 >> 3) & 63, j16 = (f2 >> 9) & 7, ks = f2 >> 12;
        int o = j16 * 16 + (l & 15);
        int k = ks * 32 + ((l >> 4) << 3) + e;
        W2f[f2] = f32_to_bf16(W2[o * D + k]);
    }
}

// R12 = R11 (best, 183.0us) + exactly one change: DEPTH-2 gather pipeline.
// Triple-buffered LDS staging, gathers issued two chunks ahead, and counted
// vmcnt(4) at each phase top (T4 idiom — never drain to 0 mid-loop).
// Issue order per phase is LOADW1 then ISSUE so the in-order vmem queue at
// the next phase top is [G_j(4), W1_j(8), G_{j+2}(4)]: vmcnt(4) retires
// exactly G_j + W1_j and leaves the next chunk's gathers in flight across
// the barrier. Each gather gets ~2 compute phases (>= ~900cyc HBM latency)
// of cover instead of 1. Cost: LDS 49.3KB -> 3 blocks/CU (12 waves vs 16).
__global__ __launch_bounds__(256, 3) void rowmlp_kernel(
    const float* __restrict__ x_rows, const int* __restrict__ seeds,
    const unsigned short* __restrict__ W1f, const float* __restrict__ b1,
    const unsigned short* __restrict__ W2f, const float* __restrict__ b2,
    float* __restrict__ out, int Nrows)
{
    __shared__ __align__(16) unsigned char smem[3][16384];
    __shared__ int sseed[BM];

    const int tid = threadIdx.x;
    const int blk = blockIdx.x;

    if (tid < BM) sseed[tid] = seeds[blk * BM + tid];
    __syncthreads();

    const int w   = tid >> 6;    // wave: stages rows 8w..8w+7; owns cols 32w..32w+31
    const int l   = tid & 63;
    const int l15 = l & 15;
    const int lhi = l >> 4;

    // staging geometry (R7/R11): instr i covers rows 8w+2i, 8w+2i+1;
    // lane covers 16B chunk c=l&31 of its row; source chunk pre-swizzled c^(r&7).
    int sbase[4], scoff[4];
    #pragma unroll
    for (int i = 0; i < 4; ++i) {
        int r = 8 * w + 2 * i + (l >> 5);
        sbase[i] = sseed[r];
        scoff[i] = ((l & 31) ^ (r & 7)) << 2;   // float offset within row
    }

    const bf16x8* W1v = (const bf16x8*)W1f;
    const bf16x8* W2v = (const bf16x8*)W2f;

#define WAIT4 asm volatile("s_waitcnt vmcnt(4)" ::: "memory")
#define WAIT0 asm volatile("s_waitcnt vmcnt(0)" ::: "memory")
#define BAR   __builtin_amdgcn_s_barrier()

#define ISSUE(J)                                                               \
    {                                                                          \
        _Pragma("unroll")                                                      \
        for (int i = 0; i < 4; ++i) {                                          \
            int idx = sbase[i] + (J) - 2;                                      \
            idx = idx < 0 ? 0 : (idx >= Nrows ? Nrows - 1 : idx);              \
            gload_lds16(x_rows + (size_t)idx * D + scoff[i],                   \
                        (void*)(smem[(J) % 3] + w * 4096 + i * 1024));         \
        }                                                                      \
    }

#define LOADW1(J, RB)                                                          \
    {                                                                          \
        _Pragma("unroll")                                                      \
        for (int ks = 0; ks < 4; ++ks)                                         \
            _Pragma("unroll")                                                  \
            for (int n = 0; n < 2; ++n)                                        \
                w1r[RB][ks][n] = W1v[(((J) * 4 + ks) * 8 + (w * 2 + n)) * 64 + l]; \
    }

#define COMPUTE(J, RB)                                                         \
    {                                                                          \
        const float* buf = (const float*)smem[(J) % 3];                        \
        _Pragma("unroll")                                                      \
        for (int ks = 0; ks < 4; ++ks) {                                       \
            bf16x8 a[2];                                                       \
            _Pragma("unroll")                                                  \
            for (int m = 0; m < 2; ++m) {                                      \
                const int r = m * 16 + l15;                                    \
                const int s = r & 7;                                           \
                const int cc = ks * 8 + lhi * 2;                               \
                float4 q0 = *(const float4*)(buf + r * 128 + (((cc) ^ s) << 2));     \
                float4 q1 = *(const float4*)(buf + r * 128 + (((cc + 1) ^ s) << 2)); \
                union { unsigned u[4]; bf16x8 v; } pk;                         \
                pk.u[0] = pack_bf16x2(q0.x, q0.y);                             \
                pk.u[1] = pack_bf16x2(q0.z, q0.w);                             \
                pk.u[2] = pack_bf16x2(q1.x, q1.y);                             \
                pk.u[3] = pack_bf16x2(q1.z, q1.w);                             \
                a[m] = pk.v;                                                   \
            }                                                                  \
            _Pragma("unroll")                                                  \
            for (int n = 0; n < 2; ++n)                                        \
                _Pragma("unroll")                                              \
                for (int m = 0; m < 2; ++m)                                    \
                    acc[m][n] = __builtin_amdgcn_mfma_f32_16x16x32_bf16(       \
                        a[m], w1r[RB][ks][n], acc[m][n], 0, 0, 0);             \
        }                                                                      \
    }

    bf16x8 w1r[2][4][2];
    f32x4 acc[2][2] = {};

    // prologue: queue = G0(4), W1_0(8), G1(4)
    ISSUE(0)
    LOADW1(0, 0)
    ISSUE(1)

    // phase 0: wait G0+W1_0, keep G1 flying
    WAIT4; BAR;
    LOADW1(1, 1) ISSUE(2)
    COMPUTE(0, 0)
    // phase 1: queue G1, W1_1, G2 -> wait G1+W1_1
    WAIT4; BAR;
    LOADW1(2, 0) ISSUE(3)
    COMPUTE(1, 1)
    // phase 2
    WAIT4; BAR;
    LOADW1(3, 1) ISSUE(4)
    COMPUTE(2, 0)
    // phase 3: no more gathers to issue
    WAIT4; BAR;
    LOADW1(4, 0)
    COMPUTE(3, 1)
    // phase 4: queue G4, W1_4 -> drain
    WAIT0; BAR;
    COMPUTE(4, 0)

    // ---- epilogue: bias + ReLU -> bf16 Hb aliased into smem[2] (buf2 idle
    // since COMPUTE(2), two barriers ago; COMPUTE(4) readers use buf1).
    unsigned short (*Hb)[D] = (unsigned short (*)[D])smem[2];
    #pragma unroll
    for (int n = 0; n < 2; ++n) {
        const int col = w * 32 + n * 16 + l15;
        const float bias = b1[col];
        #pragma unroll
        for (int m = 0; m < 2; ++m) {
            #pragma unroll
            for (int r = 0; r < 4; ++r) {
                float v = acc[m][n][r] + bias;
                v = v > 0.f ? v : 0.f;
                const int row = m * 16 + lhi * 4 + r;  // C/D: col=lane&15, row=(lane>>4)*4+reg
                Hb[row][col ^ ((row & 7) << 3)] = f32_to_bf16(v);
            }
        }
    }
    __syncthreads();

    // GEMM2: out = h @ W2^T  (M=32, N=32/wave, K=128) — reuse acc
    #pragma unroll
    for (int m = 0; m < 2; ++m)
        #pragma unroll
        for (int n = 0; n < 2; ++n)
            acc[m][n] = (f32x4){0.f, 0.f, 0.f, 0.f};
    #pragma unroll
    for (int ks = 0; ks < 4; ++ks) {
        bf16x8 a2[2], bb[2];
        #pragma unroll
        for (int m = 0; m < 2; ++m) {
            const int row = m * 16 + l15;
            a2[m] = *(const bf16x8*)(&Hb[row][(ks * 32 + lhi * 8) ^ ((row & 7) << 3)]);
        }
        #pragma unroll
        for (int n = 0; n < 2; ++n) {
            const int j16 = w * 2 + n;
            bb[n] = W2v[(ks * 8 + j16) * 64 + l];
        }
        #pragma unroll
        for (int m = 0; m < 2; ++m)
            #pragma unroll
            for (int n = 0; n < 2; ++n)
                acc[m][n] = __builtin_amdgcn_mfma_f32_16x16x32_bf16(a2[m], bb[n], acc[m][n], 0, 0, 0);
    }

    // bias + fp32 store
    #pragma unroll
    for (int n = 0; n < 2; ++n) {
        const int col = w * 32 + n * 16 + l15;
        const float bias = b2[col];
        #pragma unroll
        for (int m = 0; m < 2; ++m) {
            #pragma unroll
            for (int r = 0; r < 4; ++r) {
                const int row = m * 16 + lhi * 4 + r;
                out[(size_t)(blk * BM + row) * D + col] = acc[m][n][r] + bias;
            }
        }
    }
#undef ISSUE
#undef LOADW1
#undef COMPUTE
#undef WAIT4
#undef WAIT0
#undef BAR
}

extern "C" void kernel_launch(void* const* d_in, const int* in_sizes, int n_in,
                              void* d_out, int out_size, void* d_ws, size_t ws_size,
                              hipStream_t stream) {
    const float* x_rows = (const float*)d_in[0];
    const int*   seeds  = (const int*)d_in[1];
    const float* W1     = (const float*)d_in[2];
    const float* b1     = (const float*)d_in[3];
    const float* W2     = (const float*)d_in[4];
    const float* b2     = (const float*)d_in[5];
    float* out = (float*)d_out;

    int Nrows = in_sizes[0] / D;
    int B = in_sizes[1];

    unsigned short* W1f = (unsigned short*)d_ws;
    unsigned short* W2f = W1f + W1F_ELEMS;

    prep_frags<<<(W1F_ELEMS + W2F_ELEMS + 255) / 256, 256, 0, stream>>>(W1, W2, W1f, W2f);
    rowmlp_kernel<<<B / BM, 256, 0, stream>>>(x_rows, seeds, W1f, b1, W2f, b2, out, Nrows);
}